// Round 9
// baseline (161.530 us; speedup 1.0000x reference)
//
#include <hip/hip_runtime.h>

// SpMM out = w[idx] * segment_sum(vals[:,None] * x[cols], rows, N)
//
// Ladder lessons:
//  R1: direct f32 atomics -> 800MB write traffic (680us).
//  R5: exact-CSR scatter -> 52.5MB write amp (60us scatter).
//  R6: linked list -> 102MB metadata read amp; chains serialize.
//  R7: few-block LDS-atomic gather -> parallelism collapse (345us, warm-L3
//      latency-bound at 37GB/s -> NOT bandwidth, LATENCY is the enemy).
//  R8: bucket binning + register-accum gather = 150us total; harness ws
//      re-poison (42us fill @ 6.5TB/s) + restores are a fixed ~50us floor.
//
// R9: gather is cache-LATENCY bound; x (12.8MB) fits L3 but not one XCD's
// 4MB L2. Phase x-access by column range: gather re-sorts its bucket's
// records into per-(colrange, wave) LDS lists, then all waves sweep cr=0..3
// with barriers between phases -> per-phase XCD footprint 3.2MB -> L2-hot.
// Unroll-8, cndmask row-select into 4 register accumulators, nontemporal
// pack/out streams so they don't evict x from L2.

#define FEAT_D 64
#define BROWS 32
#define BSH 5
#define NCR 4          // column ranges: cr = col >> 14 (valid for N <= 65536)
#define CRSH 14
#define LCAP 48        // per-(cr,wave) LDS list capacity; mean load is 16
#define OVFCAP 16384
#define EPB 8192       // edges per build block
#define BBLOCK 512
#define GBLOCK 512     // 8 waves; wave w owns rows 4w..4w+3

// ---------- build: two-phase LDS-cursor binning into bucket regions ----------
// Bucket-granular key keeps write runs ~5 recs (42B) -> small write amp.
__global__ void build_kernel(const float* __restrict__ edge_vals,
                             const int* __restrict__ edge_rows,
                             const int* __restrict__ edge_cols,
                             const int* __restrict__ idx_ptr,
                             int* __restrict__ bktcnt,
                             int2* __restrict__ pack,
                             int* __restrict__ ovfcnt,
                             int4* __restrict__ ovfbuf,
                             int E, int NBKT, int cap) {
    extern __shared__ int lh[];   // NBKT counters
    const long long off = (long long)idx_ptr[0] * E;
    const int* rows = edge_rows + off;
    const int* cols = edge_cols + off;
    const float* vals = edge_vals + off;
    for (int k = threadIdx.x; k < NBKT; k += blockDim.x) lh[k] = 0;
    __syncthreads();
    const int s = blockIdx.x * EPB;
    const int e2 = min(s + EPB, E);
    for (int g = s + threadIdx.x; g < e2; g += blockDim.x)
        atomicAdd(&lh[rows[g] >> BSH], 1);
    __syncthreads();
    for (int k = threadIdx.x; k < NBKT; k += blockDim.x) {
        const int c = lh[k];
        if (c) lh[k] = atomicAdd(&bktcnt[k], c);
    }
    __syncthreads();
    for (int g = s + threadIdx.x; g < e2; g += blockDim.x) {
        const int r = rows[g], c = cols[g];
        const int b = r >> BSH;
        const int pos = atomicAdd(&lh[b], 1);
        if (pos < cap) {
            pack[(long long)b * cap + pos] =
                make_int2((c << BSH) | (r & (BROWS - 1)), __float_as_int(vals[g]));
        } else {
            const int o = atomicAdd(ovfcnt, 1);
            if (o < OVFCAP) ovfbuf[o] = make_int4(r, c, __float_as_int(vals[g]), 0);
        }
    }
}

// ---------- gather: block/bucket, cr-phased, register accumulation ----------
__global__ __launch_bounds__(GBLOCK) void gather_kernel(
        const float* __restrict__ x,
        const float* __restrict__ weight,
        const int* __restrict__ idx_ptr,
        const int* __restrict__ bktcnt,
        const int2* __restrict__ pack,
        int* __restrict__ ovfcnt, int4* __restrict__ ovfbuf,
        float* __restrict__ out, int N, int cap) {
    extern __shared__ int2 sh2[];        // [cap] staging + [NCR*8*LCAP] lists
    int2* sraw = sh2;
    int2* slist = sh2 + cap;
    __shared__ int scur[NCR * 8];
    const int b = blockIdx.x;
    const int t = threadIdx.x;
    const int w = t >> 6;                // wave 0..7 owns rows 4w..4w+3
    const int lane = t & 63;
    if (t < NCR * 8) scur[t] = 0;
    const int cnt = min(bktcnt[b], cap);
    // nontemporal stream of this bucket's records (read-once; keep L2 for x)
    const long long* psrc = (const long long*)(pack + (long long)b * cap);
    for (int i = t; i < cnt; i += GBLOCK) {
        const long long raw = __builtin_nontemporal_load(psrc + i);
        sraw[i] = make_int2((int)(unsigned)raw, (int)(raw >> 32));
    }
    __syncthreads();
    // re-sort: per-(colrange, wave) lists; rec.x = col<<5 | row_local
    for (int j = lane; j < cnt; j += 64) {
        const int2 rec = sraw[j];
        const int rl = rec.x & (BROWS - 1);
        if ((rl >> 2) == w) {
            const int cr = rec.x >> (BSH + CRSH);
            const int li = atomicAdd(&scur[cr * 8 + w], 1);
            if (li < LCAP) {
                slist[(cr * 8 + w) * LCAP + li] = rec;
            } else {
                const int o = atomicAdd(ovfcnt, 1);
                const int row = (b << BSH) | rl;
                if (o < OVFCAP) ovfbuf[o] = make_int4(row, rec.x >> BSH, rec.y, 0);
            }
        }
    }
    __syncthreads();
    float acc0 = 0.f, acc1 = 0.f, acc2 = 0.f, acc3 = 0.f;
#define EDGE(Rc, XV)                                                          \
    {                                                                         \
        const float m = __int_as_float(Rc.y) * XV;                            \
        const int q = Rc.x & 3;                                               \
        acc0 += (q == 0) ? m : 0.f;                                           \
        acc1 += (q == 1) ? m : 0.f;                                           \
        acc2 += (q == 2) ? m : 0.f;                                           \
        acc3 += (q == 3) ? m : 0.f;                                           \
    }
    for (int cr = 0; cr < NCR; ++cr) {   // phase sweep: x slice cr is L2-hot
        const int li = cr * 8 + w;
        const int n = min(scur[li], LCAP);
        const int2* lp = slist + li * LCAP;
        int j = 0;
        for (; j + 8 <= n; j += 8) {     // 8 independent x-row loads in flight
            const int2 r0 = lp[j],     r1 = lp[j + 1], r2 = lp[j + 2],
                       r3 = lp[j + 3], r4 = lp[j + 4], r5 = lp[j + 5],
                       r6 = lp[j + 6], r7 = lp[j + 7];
            const float x0 = x[(r0.x >> BSH) * FEAT_D + lane];
            const float x1 = x[(r1.x >> BSH) * FEAT_D + lane];
            const float x2 = x[(r2.x >> BSH) * FEAT_D + lane];
            const float x3 = x[(r3.x >> BSH) * FEAT_D + lane];
            const float x4 = x[(r4.x >> BSH) * FEAT_D + lane];
            const float x5 = x[(r5.x >> BSH) * FEAT_D + lane];
            const float x6 = x[(r6.x >> BSH) * FEAT_D + lane];
            const float x7 = x[(r7.x >> BSH) * FEAT_D + lane];
            EDGE(r0, x0) EDGE(r1, x1) EDGE(r2, x2) EDGE(r3, x3)
            EDGE(r4, x4) EDGE(r5, x5) EDGE(r6, x6) EDGE(r7, x7)
        }
        for (; j + 4 <= n; j += 4) {
            const int2 r0 = lp[j], r1 = lp[j + 1], r2 = lp[j + 2], r3 = lp[j + 3];
            const float x0 = x[(r0.x >> BSH) * FEAT_D + lane];
            const float x1 = x[(r1.x >> BSH) * FEAT_D + lane];
            const float x2 = x[(r2.x >> BSH) * FEAT_D + lane];
            const float x3 = x[(r3.x >> BSH) * FEAT_D + lane];
            EDGE(r0, x0) EDGE(r1, x1) EDGE(r2, x2) EDGE(r3, x3)
        }
        for (; j < n; ++j) {
            const int2 r0 = lp[j];
            const float x0 = x[(r0.x >> BSH) * FEAT_D + lane];
            EDGE(r0, x0)
        }
        __syncthreads();                 // keep waves phase-aligned on cr
    }
#undef EDGE
    const float ws = weight[idx_ptr[0]];
    const int row0 = (b << BSH) + w * 4;
    if (row0 + 0 < N)
        __builtin_nontemporal_store(ws * acc0, &out[(long long)(row0 + 0) * FEAT_D + lane]);
    if (row0 + 1 < N)
        __builtin_nontemporal_store(ws * acc1, &out[(long long)(row0 + 1) * FEAT_D + lane]);
    if (row0 + 2 < N)
        __builtin_nontemporal_store(ws * acc2, &out[(long long)(row0 + 2) * FEAT_D + lane]);
    if (row0 + 3 < N)
        __builtin_nontemporal_store(ws * acc3, &out[(long long)(row0 + 3) * FEAT_D + lane]);
}

// ---------- fixup: apply overflow records (normally zero work) ----------
__global__ void fixup_kernel(const float* __restrict__ x,
                             const float* __restrict__ weight,
                             const int* __restrict__ idx_ptr,
                             const int* __restrict__ ovfcnt,
                             const int4* __restrict__ ovfbuf,
                             float* __restrict__ out) {
    const int n = min(*ovfcnt, OVFCAP);
    if (n == 0) return;
    const float ws = weight[idx_ptr[0]];
    const int gw = (int)((blockIdx.x * (long long)blockDim.x + threadIdx.x) >> 6);
    const int lane = threadIdx.x & 63;
    const int nw = (gridDim.x * blockDim.x) >> 6;
    for (int r = gw; r < n; r += nw) {
        const int4 rec = ovfbuf[r];
        atomicAdd(&out[(long long)rec.x * FEAT_D + lane],
                  ws * __int_as_float(rec.z) * x[(long long)rec.y * FEAT_D + lane]);
    }
}

// ---------- fallback (direct atomic scatter, always correct) ----------
__global__ void spmm_scatter_kernel(const float* __restrict__ x,
                                    const float* __restrict__ weight,
                                    const float* __restrict__ edge_vals,
                                    const int* __restrict__ edge_rows,
                                    const int* __restrict__ edge_cols,
                                    const int* __restrict__ idx_ptr,
                                    float* __restrict__ out,
                                    int E, long long work) {
    const int idx = idx_ptr[0];
    const float w = weight[idx];
    const long long rel_off = (long long)idx * E;
    long long t = (long long)blockIdx.x * blockDim.x + threadIdx.x;
    if (t >= work) return;
    const int e = (int)(t >> 4);
    const int q = (int)(t & 15);
    const int r = edge_rows[rel_off + e];
    const int c = edge_cols[rel_off + e];
    const float wv = w * edge_vals[rel_off + e];
    const float4 xv = *reinterpret_cast<const float4*>(x + (long long)c * FEAT_D + q * 4);
    float* op = out + (long long)r * FEAT_D + q * 4;
    atomicAdd(op + 0, wv * xv.x);
    atomicAdd(op + 1, wv * xv.y);
    atomicAdd(op + 2, wv * xv.z);
    atomicAdd(op + 3, wv * xv.w);
}

extern "C" void kernel_launch(void* const* d_in, const int* in_sizes, int n_in,
                              void* d_out, int out_size, void* d_ws, size_t ws_size,
                              hipStream_t stream) {
    const float* x         = (const float*)d_in[0];
    const float* weight    = (const float*)d_in[1];
    const float* edge_vals = (const float*)d_in[2];
    const int*   edge_rows = (const int*)d_in[3];
    const int*   edge_cols = (const int*)d_in[4];
    const int*   idx_ptr   = (const int*)d_in[5];
    float* out = (float*)d_out;

    const int R = in_sizes[1];
    const int E = in_sizes[2] / R;
    const int N = in_sizes[0] / FEAT_D;
    const int NBKT = (N + BROWS - 1) >> BSH;

    // ws layout: bktcnt[NBKT] | ovfcnt | pad | ovfbuf[OVFCAP]x16B | pack
    char* ws = (char*)d_ws;
    size_t o_bktcnt = 0;
    size_t o_ovfcnt = o_bktcnt + (size_t)NBKT * 4;
    size_t o_ovfbuf = ((o_ovfcnt + 4 + 15) / 16) * 16;
    size_t o_pack   = o_ovfbuf + (size_t)OVFCAP * 16;
    const size_t room = (ws_size > o_pack) ? (ws_size - o_pack) : 0;
    int cap = (int)(room / ((size_t)NBKT * 8));
    if (cap > 1024) cap = 1024;

    const long long meanload = (NBKT > 0) ? ((long long)E / NBKT) : 0;
    if (cap < 64 || cap < meanload + (meanload >> 3) + 16 || NBKT > 8192 ||
        N > (1 << (CRSH + 2))) {
        hipMemsetAsync(d_out, 0, (size_t)out_size * sizeof(float), stream);
        const long long work = (long long)E * 16;
        const int block = 256;
        const long long grid = (work + block - 1) / block;
        spmm_scatter_kernel<<<dim3((unsigned)grid), dim3(block), 0, stream>>>(
            x, weight, edge_vals, edge_rows, edge_cols, idx_ptr, out, E, work);
        return;
    }

    int*  bktcnt = (int*)(ws + o_bktcnt);
    int*  ovfcnt = (int*)(ws + o_ovfcnt);
    int4* ovfbuf = (int4*)(ws + o_ovfbuf);
    int2* pack   = (int2*)(ws + o_pack);

    hipMemsetAsync(bktcnt, 0, (size_t)NBKT * 4 + 4, stream);

    const int bgrid = (E + EPB - 1) / EPB;
    const size_t blds = (size_t)NBKT * 4;
    build_kernel<<<bgrid, BBLOCK, blds, stream>>>(edge_vals, edge_rows,
                                                  edge_cols, idx_ptr, bktcnt,
                                                  pack, ovfcnt, ovfbuf,
                                                  E, NBKT, cap);

    const size_t glds = ((size_t)cap + NCR * 8 * LCAP) * 8;
    gather_kernel<<<NBKT, GBLOCK, glds, stream>>>(x, weight, idx_ptr, bktcnt,
                                                  pack, ovfcnt, ovfbuf,
                                                  out, N, cap);

    fixup_kernel<<<64, 256, 0, stream>>>(x, weight, idx_ptr, ovfcnt, ovfbuf, out);
}

// Round 10
// 138.825 us; speedup vs baseline: 1.1636x; 1.1636x over previous
//
#include <hip/hip_runtime.h>

// SpMM out = w[idx] * segment_sum(vals[:,None] * x[cols], rows, N)
//
// Ladder: R1 direct atomics 680us -> R5 CSR sort 339->232us (52MB write amp)
// -> R6 linked list (102MB read amp, bad) -> R8 bucket binning + register
// gather 150.5us -> R9 cr-phasing + cndmask REGRESSED (VALU-bound, 51% busy).
//
// R10: R8 structure, minus its waste:
//  gather: ONE cooperative distribution pass (512 threads read pack straight
//  from global, place into 32 per-row LDS lists), then wave w register-
//  accumulates rows 4w..4w+3 unroll-4. No staging, no 8x duplicate scan,
//  no cndmask.
//  build: EPB 4096 (196 blocks, ~2x wave count of R8's 98), row indices
//  cached in registers between count and place passes.
// Harness fill/restore (~50us: 256MiB ws poison @6.5TB/s + in/out) is a
// fixed floor inside the timed window.

#define FEAT_D 64
#define BROWS 32
#define BSH 5
#define LCAP 48        // per-row LDS list cap; degree ~Poisson(16), P(>48)~1e-11
#define OVFCAP 16384
#define EPB 4096       // edges per build block
#define BBLOCK 512
#define EPT (EPB / BBLOCK)   // 8 edges per thread, rows cached in regs
#define GBLOCK 512     // 8 waves; wave w owns local rows 4w..4w+3

// ---------- build: two-phase LDS-cursor binning into bucket regions ----------
__global__ __launch_bounds__(BBLOCK) void build_kernel(
        const float* __restrict__ edge_vals,
        const int* __restrict__ edge_rows,
        const int* __restrict__ edge_cols,
        const int* __restrict__ idx_ptr,
        int* __restrict__ bktcnt,
        int2* __restrict__ pack,
        int* __restrict__ ovfcnt,
        int4* __restrict__ ovfbuf,
        int E, int NBKT, int cap) {
    extern __shared__ int lh[];   // NBKT counters
    const long long off = (long long)idx_ptr[0] * E;
    const int* rows = edge_rows + off;
    const int* cols = edge_cols + off;
    const float* vals = edge_vals + off;
    for (int k = threadIdx.x; k < NBKT; k += BBLOCK) lh[k] = 0;
    __syncthreads();
    const int s = blockIdx.x * EPB;
    const int e2 = min(s + EPB, E);
    int myrow[EPT];
    // pass 1: count (rows cached in registers)
#pragma unroll
    for (int k = 0; k < EPT; ++k) {
        const int g = s + threadIdx.x + k * BBLOCK;
        if (g < e2) {
            const int r = rows[g];
            myrow[k] = r;
            atomicAdd(&lh[r >> BSH], 1);
        }
    }
    __syncthreads();
    // pass 2: reserve disjoint global runs; lh[k] becomes this block's cursor
    for (int k = threadIdx.x; k < NBKT; k += BBLOCK) {
        const int c = lh[k];
        if (c) lh[k] = atomicAdd(&bktcnt[k], c);
    }
    __syncthreads();
    // pass 3: place records (col<<5 | row_local, val)
#pragma unroll
    for (int k = 0; k < EPT; ++k) {
        const int g = s + threadIdx.x + k * BBLOCK;
        if (g < e2) {
            const int r = myrow[k];
            const int b = r >> BSH;
            const int c = cols[g];
            const float v = vals[g];
            const int pos = atomicAdd(&lh[b], 1);
            if (pos < cap) {
                pack[(long long)b * cap + pos] =
                    make_int2((c << BSH) | (r & (BROWS - 1)), __float_as_int(v));
            } else {
                const int o = atomicAdd(ovfcnt, 1);
                if (o < OVFCAP) ovfbuf[o] = make_int4(r, c, __float_as_int(v), 0);
            }
        }
    }
}

// ---------- gather: block/bucket, 1-pass distribute, register accum ----------
__global__ __launch_bounds__(GBLOCK) void gather_kernel(
        const float* __restrict__ x,
        const float* __restrict__ weight,
        const int* __restrict__ idx_ptr,
        const int* __restrict__ bktcnt,
        const int2* __restrict__ pack,
        int* __restrict__ ovfcnt, int4* __restrict__ ovfbuf,
        float* __restrict__ out, int N, int cap) {
    __shared__ int2 slist[BROWS * LCAP];   // 12.3 KB
    __shared__ int scur[BROWS];
    const int b = blockIdx.x;
    const int t = threadIdx.x;
    const int w = t >> 6;                  // wave 0..7
    const int lane = t & 63;
    if (t < BROWS) scur[t] = 0;
    __syncthreads();
    const int cnt = min(bktcnt[b], cap);
    // cooperative distribution: all threads split the record stream once.
    // nontemporal: pack is read-once; don't evict x from L2.
    const long long* psrc = (const long long*)(pack + (long long)b * cap);
    for (int j = t; j < cnt; j += GBLOCK) {
        const long long raw = __builtin_nontemporal_load(psrc + j);
        const int2 rec = make_int2((int)(unsigned)raw, (int)(raw >> 32));
        const int rl = rec.x & (BROWS - 1);
        const int li = atomicAdd(&scur[rl], 1);
        if (li < LCAP) {
            slist[rl * LCAP + li] = rec;
        } else {
            const int o = atomicAdd(ovfcnt, 1);
            const int row = (b << BSH) | rl;
            if (o < OVFCAP) ovfbuf[o] = make_int4(row, rec.x >> BSH, rec.y, 0);
        }
    }
    __syncthreads();
    const float ws = weight[idx_ptr[0]];
    float acc0 = 0.f, acc1 = 0.f, acc2 = 0.f, acc3 = 0.f;
#define ROWACC(Q, ACC)                                                        \
    {                                                                         \
        const int rl = w * 4 + Q;                                             \
        const int n = min(scur[rl], LCAP);                                    \
        const int2* lp = slist + rl * LCAP;                                   \
        int j = 0;                                                            \
        for (; j + 4 <= n; j += 4) {                                          \
            const int2 r0 = lp[j], r1 = lp[j + 1], r2 = lp[j + 2],            \
                       r3 = lp[j + 3];                                        \
            const float x0 = x[(r0.x >> BSH) * FEAT_D + lane];                \
            const float x1 = x[(r1.x >> BSH) * FEAT_D + lane];                \
            const float x2 = x[(r2.x >> BSH) * FEAT_D + lane];                \
            const float x3 = x[(r3.x >> BSH) * FEAT_D + lane];                \
            ACC += __int_as_float(r0.y) * x0 + __int_as_float(r1.y) * x1 +    \
                   __int_as_float(r2.y) * x2 + __int_as_float(r3.y) * x3;     \
        }                                                                     \
        for (; j < n; ++j) {                                                  \
            const int2 r0 = lp[j];                                            \
            ACC += __int_as_float(r0.y) * x[(r0.x >> BSH) * FEAT_D + lane];   \
        }                                                                     \
    }
    ROWACC(0, acc0)
    ROWACC(1, acc1)
    ROWACC(2, acc2)
    ROWACC(3, acc3)
#undef ROWACC
    const int row0 = (b << BSH) + w * 4;
    if (row0 + 0 < N)
        __builtin_nontemporal_store(ws * acc0, &out[(long long)(row0 + 0) * FEAT_D + lane]);
    if (row0 + 1 < N)
        __builtin_nontemporal_store(ws * acc1, &out[(long long)(row0 + 1) * FEAT_D + lane]);
    if (row0 + 2 < N)
        __builtin_nontemporal_store(ws * acc2, &out[(long long)(row0 + 2) * FEAT_D + lane]);
    if (row0 + 3 < N)
        __builtin_nontemporal_store(ws * acc3, &out[(long long)(row0 + 3) * FEAT_D + lane]);
}

// ---------- fixup: apply overflow records (normally zero work) ----------
__global__ void fixup_kernel(const float* __restrict__ x,
                             const float* __restrict__ weight,
                             const int* __restrict__ idx_ptr,
                             const int* __restrict__ ovfcnt,
                             const int4* __restrict__ ovfbuf,
                             float* __restrict__ out) {
    const int n = min(*ovfcnt, OVFCAP);
    if (n == 0) return;
    const float ws = weight[idx_ptr[0]];
    const int gw = (int)((blockIdx.x * (long long)blockDim.x + threadIdx.x) >> 6);
    const int lane = threadIdx.x & 63;
    const int nw = (gridDim.x * blockDim.x) >> 6;
    for (int r = gw; r < n; r += nw) {
        const int4 rec = ovfbuf[r];
        atomicAdd(&out[(long long)rec.x * FEAT_D + lane],
                  ws * __int_as_float(rec.z) * x[(long long)rec.y * FEAT_D + lane]);
    }
}

// ---------- fallback (direct atomic scatter, always correct) ----------
__global__ void spmm_scatter_kernel(const float* __restrict__ x,
                                    const float* __restrict__ weight,
                                    const float* __restrict__ edge_vals,
                                    const int* __restrict__ edge_rows,
                                    const int* __restrict__ edge_cols,
                                    const int* __restrict__ idx_ptr,
                                    float* __restrict__ out,
                                    int E, long long work) {
    const int idx = idx_ptr[0];
    const float w = weight[idx];
    const long long rel_off = (long long)idx * E;
    long long t = (long long)blockIdx.x * blockDim.x + threadIdx.x;
    if (t >= work) return;
    const int e = (int)(t >> 4);
    const int q = (int)(t & 15);
    const int r = edge_rows[rel_off + e];
    const int c = edge_cols[rel_off + e];
    const float wv = w * edge_vals[rel_off + e];
    const float4 xv = *reinterpret_cast<const float4*>(x + (long long)c * FEAT_D + q * 4);
    float* op = out + (long long)r * FEAT_D + q * 4;
    atomicAdd(op + 0, wv * xv.x);
    atomicAdd(op + 1, wv * xv.y);
    atomicAdd(op + 2, wv * xv.z);
    atomicAdd(op + 3, wv * xv.w);
}

extern "C" void kernel_launch(void* const* d_in, const int* in_sizes, int n_in,
                              void* d_out, int out_size, void* d_ws, size_t ws_size,
                              hipStream_t stream) {
    const float* x         = (const float*)d_in[0];
    const float* weight    = (const float*)d_in[1];
    const float* edge_vals = (const float*)d_in[2];
    const int*   edge_rows = (const int*)d_in[3];
    const int*   edge_cols = (const int*)d_in[4];
    const int*   idx_ptr   = (const int*)d_in[5];
    float* out = (float*)d_out;

    const int R = in_sizes[1];
    const int E = in_sizes[2] / R;
    const int N = in_sizes[0] / FEAT_D;
    const int NBKT = (N + BROWS - 1) >> BSH;

    // ws layout: bktcnt[NBKT] | ovfcnt | pad | ovfbuf[OVFCAP]x16B | pack
    char* ws = (char*)d_ws;
    size_t o_bktcnt = 0;
    size_t o_ovfcnt = o_bktcnt + (size_t)NBKT * 4;
    size_t o_ovfbuf = ((o_ovfcnt + 4 + 15) / 16) * 16;
    size_t o_pack   = o_ovfbuf + (size_t)OVFCAP * 16;
    const size_t room = (ws_size > o_pack) ? (ws_size - o_pack) : 0;
    int cap = (int)(room / ((size_t)NBKT * 8));
    if (cap > 1024) cap = 1024;

    const long long meanload = (NBKT > 0) ? ((long long)E / NBKT) : 0;
    if (cap < 64 || cap < meanload + (meanload >> 3) + 16 || NBKT > 8192) {
        hipMemsetAsync(d_out, 0, (size_t)out_size * sizeof(float), stream);
        const long long work = (long long)E * 16;
        const int block = 256;
        const long long grid = (work + block - 1) / block;
        spmm_scatter_kernel<<<dim3((unsigned)grid), dim3(block), 0, stream>>>(
            x, weight, edge_vals, edge_rows, edge_cols, idx_ptr, out, E, work);
        return;
    }

    int*  bktcnt = (int*)(ws + o_bktcnt);
    int*  ovfcnt = (int*)(ws + o_ovfcnt);
    int4* ovfbuf = (int4*)(ws + o_ovfbuf);
    int2* pack   = (int2*)(ws + o_pack);

    hipMemsetAsync(bktcnt, 0, (size_t)NBKT * 4 + 4, stream);

    const int bgrid = (E + EPB - 1) / EPB;
    const size_t blds = (size_t)NBKT * 4;
    build_kernel<<<bgrid, BBLOCK, blds, stream>>>(edge_vals, edge_rows,
                                                  edge_cols, idx_ptr, bktcnt,
                                                  pack, ovfcnt, ovfbuf,
                                                  E, NBKT, cap);

    gather_kernel<<<NBKT, GBLOCK, 0, stream>>>(x, weight, idx_ptr, bktcnt,
                                               pack, ovfcnt, ovfbuf,
                                               out, N, cap);

    fixup_kernel<<<64, 256, 0, stream>>>(x, weight, idx_ptr, ovfcnt, ovfbuf, out);
}

// Round 11
// 135.556 us; speedup vs baseline: 1.1916x; 1.0241x over previous
//
#include <hip/hip_runtime.h>

// SpMM out = w[idx] * segment_sum(vals[:,None] * x[cols], rows, N)
//
// Ladder: R1 atomics 680us -> R5 CSR sort 232 (52MB write amp) -> R6 linked
// list (read amp) -> R8 bucket-bin + reg-gather 150.5 -> R9 cndmask regress
// -> R10 1-pass distribute 138.8. Harness fill/restore ~57us is fixed floor;
// build (~40us, scattered 8B stores) is the biggest controllable piece.
//
// R11: build = LDS-staged per-block counting sort -> copy-out is LINEAR
// (consecutive threads -> consecutive global addrs within bucket runs);
// BROWS 64 doubles run length (~5.2 recs @ EPB 4096). Gather: wave owns
// 8 rows, register accumulation, unroll-4 (R10 structure, BROWS-64 geometry).

#define FEAT_D 64
#define BROWS 64
#define BSH 6
#define MAXBKT 1024     // N <= 65536
#define LCAP 44         // per-row list cap; deg~Poisson(16), P(>44) ~ 1e-9
#define OVFCAP 16384
#define EPB 4096        // edges per build block
#define BBLOCK 512
#define EPT (EPB / BBLOCK)   // 8
#define GBLOCK 512      // 8 waves; wave w owns rows 8w..8w+7

// ---------- build: LDS-staged counting sort, coalesced copy-out ----------
__global__ __launch_bounds__(BBLOCK) void build_kernel(
        const float* __restrict__ edge_vals,
        const int* __restrict__ edge_rows,
        const int* __restrict__ edge_cols,
        const int* __restrict__ idx_ptr,
        int* __restrict__ bktcnt,
        int2* __restrict__ pack,
        int* __restrict__ ovfcnt,
        int4* __restrict__ ovfbuf,
        int E, int NBKT, int cap) {
    __shared__ int2 stage[EPB];            // 32 KB bucket-ordered records
    __shared__ unsigned short sbkt[EPB];   // 8 KB bucket id per staged slot
    __shared__ int lh[MAXBKT];             // counts -> cursors
    __shared__ int lofs[MAXBKT];           // local exclusive offsets
    __shared__ int gbase[MAXBKT];          // reserved global run bases
    __shared__ int ssum[BBLOCK];
    const long long off = (long long)idx_ptr[0] * E;
    const int* rows = edge_rows + off;
    const int* cols = edge_cols + off;
    const float* vals = edge_vals + off;
    const int t = threadIdx.x;
    const int s = blockIdx.x * EPB;
    const int e2 = min(s + EPB, E);
    const int cnt_total = e2 - s;

    for (int k = t; k < NBKT; k += BBLOCK) lh[k] = 0;
    __syncthreads();

    // p1: count; cache record + bucket in registers
    int2 myrec[EPT];
    int mybkt[EPT];
#pragma unroll
    for (int k = 0; k < EPT; ++k) {
        const int g = s + t + k * BBLOCK;
        mybkt[k] = -1;
        if (g < e2) {
            const int r = rows[g];
            const int c = cols[g];
            const float v = vals[g];
            mybkt[k] = r >> BSH;
            myrec[k] = make_int2((c << BSH) | (r & (BROWS - 1)), __float_as_int(v));
            atomicAdd(&lh[mybkt[k]], 1);
        }
    }
    __syncthreads();

    // p2: block-local exclusive scan of lh -> lofs (2 elems/thread)
    const int i0 = 2 * t, i1 = 2 * t + 1;
    const int a0 = (i0 < NBKT) ? lh[i0] : 0;
    const int a1 = (i1 < NBKT) ? lh[i1] : 0;
    ssum[t] = a0 + a1;
    __syncthreads();
    for (int d = 1; d < BBLOCK; d <<= 1) {
        const int add = (t >= d) ? ssum[t - d] : 0;
        __syncthreads();
        ssum[t] += add;
        __syncthreads();
    }
    const int exc = ssum[t] - (a0 + a1);
    if (i0 < NBKT) lofs[i0] = exc;
    if (i1 < NBKT) lofs[i1] = exc + a0;
    __syncthreads();

    // cursors = lofs
    for (int k = t; k < NBKT; k += BBLOCK) lh[k] = lofs[k];
    __syncthreads();

    // p3: place records into LDS in bucket order
#pragma unroll
    for (int k = 0; k < EPT; ++k) {
        if (mybkt[k] >= 0) {
            const int pos = atomicAdd(&lh[mybkt[k]], 1);
            stage[pos] = myrec[k];
            sbkt[pos] = (unsigned short)mybkt[k];
        }
    }
    __syncthreads();

    // p4: reserve global runs (count = final cursor - lofs)
    for (int k = t; k < NBKT; k += BBLOCK) {
        const int c = lh[k] - lofs[k];
        gbase[k] = (c > 0) ? atomicAdd(&bktcnt[k], c) : 0;
    }
    __syncthreads();

    // p5: linear copy-out; consecutive threads -> consecutive global addrs
    for (int p = t; p < cnt_total; p += BBLOCK) {
        const int k = sbkt[p];
        const int g = gbase[k] + (p - lofs[k]);
        const int2 rec = stage[p];
        if (g < cap) {
            __builtin_nontemporal_store(
                *(const long long*)&rec,
                (long long*)(pack + (long long)k * cap + g));
        } else {
            const int o = atomicAdd(ovfcnt, 1);
            if (o < OVFCAP)
                ovfbuf[o] = make_int4((k << BSH) | (rec.x & (BROWS - 1)),
                                      rec.x >> BSH, rec.y, 0);
        }
    }
}

// ---------- gather: block/bucket, 1-pass distribute, register accum ----------
__global__ __launch_bounds__(GBLOCK) void gather_kernel(
        const float* __restrict__ x,
        const float* __restrict__ weight,
        const int* __restrict__ idx_ptr,
        const int* __restrict__ bktcnt,
        const int2* __restrict__ pack,
        int* __restrict__ ovfcnt, int4* __restrict__ ovfbuf,
        float* __restrict__ out, int N, int cap) {
    __shared__ int2 slist[BROWS * LCAP];   // 22.5 KB
    __shared__ int scur[BROWS];
    const int b = blockIdx.x;
    const int t = threadIdx.x;
    const int w = t >> 6;                  // wave 0..7 owns rows 8w..8w+7
    const int lane = t & 63;
    if (t < BROWS) scur[t] = 0;
    __syncthreads();
    const int cnt = min(bktcnt[b], cap);
    const long long* psrc = (const long long*)(pack + (long long)b * cap);
    for (int j = t; j < cnt; j += GBLOCK) {
        const long long raw = __builtin_nontemporal_load(psrc + j);
        const int2 rec = make_int2((int)(unsigned)raw, (int)(raw >> 32));
        const int rl = rec.x & (BROWS - 1);
        const int li = atomicAdd(&scur[rl], 1);
        if (li < LCAP) {
            slist[rl * LCAP + li] = rec;
        } else {
            const int o = atomicAdd(ovfcnt, 1);
            if (o < OVFCAP)
                ovfbuf[o] = make_int4((b << BSH) | rl, rec.x >> BSH, rec.y, 0);
        }
    }
    __syncthreads();
    const float ws = weight[idx_ptr[0]];
    float acc[8];
#pragma unroll
    for (int q = 0; q < 8; ++q) acc[q] = 0.f;
#pragma unroll
    for (int q = 0; q < 8; ++q) {
        const int rl = w * 8 + q;
        const int n = min(scur[rl], LCAP);
        const int2* lp = slist + rl * LCAP;
        int j = 0;
        for (; j + 4 <= n; j += 4) {
            const int2 r0 = lp[j], r1 = lp[j + 1], r2 = lp[j + 2], r3 = lp[j + 3];
            const float x0 = x[(r0.x >> BSH) * FEAT_D + lane];
            const float x1 = x[(r1.x >> BSH) * FEAT_D + lane];
            const float x2 = x[(r2.x >> BSH) * FEAT_D + lane];
            const float x3 = x[(r3.x >> BSH) * FEAT_D + lane];
            acc[q] += __int_as_float(r0.y) * x0 + __int_as_float(r1.y) * x1 +
                      __int_as_float(r2.y) * x2 + __int_as_float(r3.y) * x3;
        }
        for (; j < n; ++j) {
            const int2 r0 = lp[j];
            acc[q] += __int_as_float(r0.y) * x[(r0.x >> BSH) * FEAT_D + lane];
        }
    }
    const int row0 = (b << BSH) + w * 8;
#pragma unroll
    for (int q = 0; q < 8; ++q) {
        const int row = row0 + q;
        if (row < N)
            __builtin_nontemporal_store(ws * acc[q],
                                        &out[(long long)row * FEAT_D + lane]);
    }
}

// ---------- fixup: apply overflow records (normally zero work) ----------
__global__ void fixup_kernel(const float* __restrict__ x,
                             const float* __restrict__ weight,
                             const int* __restrict__ idx_ptr,
                             const int* __restrict__ ovfcnt,
                             const int4* __restrict__ ovfbuf,
                             float* __restrict__ out) {
    const int n = min(*ovfcnt, OVFCAP);
    if (n == 0) return;
    const float ws = weight[idx_ptr[0]];
    const int gw = (int)((blockIdx.x * (long long)blockDim.x + threadIdx.x) >> 6);
    const int lane = threadIdx.x & 63;
    const int nw = (gridDim.x * blockDim.x) >> 6;
    for (int r = gw; r < n; r += nw) {
        const int4 rec = ovfbuf[r];
        atomicAdd(&out[(long long)rec.x * FEAT_D + lane],
                  ws * __int_as_float(rec.z) * x[(long long)rec.y * FEAT_D + lane]);
    }
}

// ---------- fallback (direct atomic scatter, always correct) ----------
__global__ void spmm_scatter_kernel(const float* __restrict__ x,
                                    const float* __restrict__ weight,
                                    const float* __restrict__ edge_vals,
                                    const int* __restrict__ edge_rows,
                                    const int* __restrict__ edge_cols,
                                    const int* __restrict__ idx_ptr,
                                    float* __restrict__ out,
                                    int E, long long work) {
    const int idx = idx_ptr[0];
    const float w = weight[idx];
    const long long rel_off = (long long)idx * E;
    long long t = (long long)blockIdx.x * blockDim.x + threadIdx.x;
    if (t >= work) return;
    const int e = (int)(t >> 4);
    const int q = (int)(t & 15);
    const int r = edge_rows[rel_off + e];
    const int c = edge_cols[rel_off + e];
    const float wv = w * edge_vals[rel_off + e];
    const float4 xv = *reinterpret_cast<const float4*>(x + (long long)c * FEAT_D + q * 4);
    float* op = out + (long long)r * FEAT_D + q * 4;
    atomicAdd(op + 0, wv * xv.x);
    atomicAdd(op + 1, wv * xv.y);
    atomicAdd(op + 2, wv * xv.z);
    atomicAdd(op + 3, wv * xv.w);
}

extern "C" void kernel_launch(void* const* d_in, const int* in_sizes, int n_in,
                              void* d_out, int out_size, void* d_ws, size_t ws_size,
                              hipStream_t stream) {
    const float* x         = (const float*)d_in[0];
    const float* weight    = (const float*)d_in[1];
    const float* edge_vals = (const float*)d_in[2];
    const int*   edge_rows = (const int*)d_in[3];
    const int*   edge_cols = (const int*)d_in[4];
    const int*   idx_ptr   = (const int*)d_in[5];
    float* out = (float*)d_out;

    const int R = in_sizes[1];
    const int E = in_sizes[2] / R;
    const int N = in_sizes[0] / FEAT_D;
    const int NBKT = (N + BROWS - 1) >> BSH;

    // ws layout: bktcnt[NBKT] | ovfcnt | pad | ovfbuf[OVFCAP]x16B | pack
    char* ws = (char*)d_ws;
    size_t o_bktcnt = 0;
    size_t o_ovfcnt = o_bktcnt + (size_t)NBKT * 4;
    size_t o_ovfbuf = ((o_ovfcnt + 4 + 15) / 16) * 16;
    size_t o_pack   = o_ovfbuf + (size_t)OVFCAP * 16;
    const size_t room = (ws_size > o_pack) ? (ws_size - o_pack) : 0;
    int cap = (int)(room / ((size_t)NBKT * 8));
    if (cap > 2048) cap = 2048;

    const long long meanload = (NBKT > 0) ? ((long long)E / NBKT) : 0;
    if (cap < 128 || cap < meanload + (meanload >> 3) + 32 || NBKT > MAXBKT) {
        hipMemsetAsync(d_out, 0, (size_t)out_size * sizeof(float), stream);
        const long long work = (long long)E * 16;
        const int block = 256;
        const long long grid = (work + block - 1) / block;
        spmm_scatter_kernel<<<dim3((unsigned)grid), dim3(block), 0, stream>>>(
            x, weight, edge_vals, edge_rows, edge_cols, idx_ptr, out, E, work);
        return;
    }

    int*  bktcnt = (int*)(ws + o_bktcnt);
    int*  ovfcnt = (int*)(ws + o_ovfcnt);
    int4* ovfbuf = (int4*)(ws + o_ovfbuf);
    int2* pack   = (int2*)(ws + o_pack);

    hipMemsetAsync(bktcnt, 0, (size_t)NBKT * 4 + 4, stream);

    const int bgrid = (E + EPB - 1) / EPB;
    build_kernel<<<bgrid, BBLOCK, 0, stream>>>(edge_vals, edge_rows,
                                               edge_cols, idx_ptr, bktcnt,
                                               pack, ovfcnt, ovfbuf,
                                               E, NBKT, cap);

    gather_kernel<<<NBKT, GBLOCK, 0, stream>>>(x, weight, idx_ptr, bktcnt,
                                               pack, ovfcnt, ovfbuf,
                                               out, N, cap);

    fixup_kernel<<<64, 256, 0, stream>>>(x, weight, idx_ptr, ovfcnt, ovfbuf, out);
}